// Round 1
// baseline (1760.636 us; speedup 1.0000x reference)
//
#include <hip/hip_runtime.h>
#include <math.h>

#define D 4096
#define K 128
#define KP 129          // K+1 (augmented sqrt(EPS)*ones column)
#define VPAD 160        // padded column count for V / Y (zeros in pad)
#define NROWS 8192
#define QS 144          // Q row stride (9 tiles of 16)
#define MS 132          // M row stride
#define LOG2PI 1.8378770664093453

// ---------------- helpers ----------------
__device__ __forceinline__ float blockReduceSum(float v) {
  #pragma unroll
  for (int off = 32; off > 0; off >>= 1) v += __shfl_down(v, off, 64);
  __shared__ float tmp[4];
  __syncthreads();                       // protect tmp across repeated calls
  if ((threadIdx.x & 63) == 0) tmp[threadIdx.x >> 6] = v;
  __syncthreads();
  float r = 0.0f;
  if (threadIdx.x == 0) r = tmp[0] + tmp[1] + tmp[2] + tmp[3];
  return r;                              // valid on tid 0 only
}

// ---------------- V and V^T: V[d][c] = U[d][c]/sigma[d] ----------------
// U[:, c<K] = W[:,c]*alpha[c];  U[:, K] = sqrt(EPS) = 1e-3
__global__ __launch_bounds__(256) void k_prep(const float* __restrict__ theta,
                                              float* __restrict__ V,
                                              float* __restrict__ VT) {
  int d = blockIdx.x * 256 + threadIdx.x;
  if (d >= D) return;
  float invs = 1.0f / theta[D * K + D + d];      // 1/sigma[d]
  for (int c = 0; c < VPAD; ++c) {
    float v;
    if (c < K)       v = theta[d * K + c] * theta[D * K + 2 * D + c] * invs;
    else if (c == K) v = 1.0e-3f * invs;
    else             v = 0.0f;
    V[d * VPAD + c] = v;
    if (c < KP) VT[c * D + d] = v;
  }
}

// ---------------- column stats of x ----------------
__global__ __launch_bounds__(256) void k_colstats(const float* __restrict__ x,
                                                  float* __restrict__ colsum,
                                                  float* __restrict__ colsumsq) {
  int d = blockIdx.x * 256 + threadIdx.x;
  int i0 = blockIdx.y * 256;
  float s1 = 0.0f, s2 = 0.0f;
  for (int i = i0; i < i0 + 256; ++i) {
    float v = x[i * D + d];
    s1 += v; s2 += v * v;
  }
  atomicAdd(&colsum[d], s1);
  atomicAdd(&colsumsq[d], s2);
}

// ---------------- M = I + V^T diag(sigma) V  (129x129) ----------------
__global__ __launch_bounds__(256) void k_M(const float* __restrict__ theta,
                                           const float* __restrict__ VT,
                                           float* __restrict__ M) {
  int j = blockIdx.x, k = blockIdx.y;
  if (k < j) return;                     // symmetry
  const float* sg = theta + D * K + D;
  float acc = 0.0f;
  for (int d = threadIdx.x; d < D; d += 256)
    acc += sg[d] * VT[j * D + d] * VT[k * D + d];
  float r = blockReduceSum(acc);
  if (threadIdx.x == 0) {
    float m = r + (j == k ? 1.0f : 0.0f);
    M[j * MS + k] = m;
    M[k * MS + j] = m;
  }
}

// ---------------- scalars: sum(log sigma), term1 ----------------
__global__ __launch_bounds__(256) void k_scalars(const float* __restrict__ theta,
                                                 const float* __restrict__ colsum,
                                                 const float* __restrict__ colsumsq,
                                                 float* __restrict__ scalars) {
  const float* mu = theta + D * K;
  const float* sg = theta + D * K + D;
  float a = 0.0f, b = 0.0f;
  for (int d = threadIdx.x; d < D; d += 256) {
    float s = sg[d];
    float m = mu[d];
    a += logf(s);
    b += (colsumsq[d] - 2.0f * m * colsum[d] + (float)NROWS * m * m) / s;
  }
  float ra = blockReduceSum(a);
  float rb = blockReduceSum(b);
  if (threadIdx.x == 0) { scalars[0] = ra; scalars[1] = rb; }
}

// ---------------- t = V^T colsum, m = V^T mu ----------------
__global__ __launch_bounds__(256) void k_smallvecs(const float* __restrict__ theta,
                                                   const float* __restrict__ VT,
                                                   const float* __restrict__ colsum,
                                                   float* __restrict__ tvec,
                                                   float* __restrict__ mvec) {
  int c = blockIdx.x;
  int which = blockIdx.y;
  const float* src = (which == 0) ? colsum : (theta + D * K);
  float a = 0.0f;
  for (int d = threadIdx.x; d < D; d += 256) a += VT[c * D + d] * src[d];
  float r = blockReduceSum(a);
  if (threadIdx.x == 0) { if (which == 0) tvec[c] = r; else mvec[c] = r; }
}

// ---------------- Y = X * V  (8192 x 4096 x 160) ----------------
#define BM 32
#define BK 32
__global__ __launch_bounds__(256) void k_gemm(const float* __restrict__ x,
                                              const float* __restrict__ V,
                                              float* __restrict__ Y) {
  __shared__ float Xs[BM][BK + 1];
  __shared__ float Vs[BK][VPAD];
  int row0 = blockIdx.x * BM;
  int tid = threadIdx.x;
  int tx = tid & 31, ty = tid >> 5;
  float acc[4][5] = {};
  for (int d0 = 0; d0 < D; d0 += BK) {
    #pragma unroll
    for (int i = 0; i < 4; ++i) {
      int idx = tid + 256 * i;
      int r = idx >> 5, kk = idx & 31;
      Xs[r][kk] = x[(row0 + r) * D + d0 + kk];
    }
    #pragma unroll
    for (int i = 0; i < 20; ++i) {
      int idx = tid + 256 * i;
      int dd = idx / VPAD, cc = idx - dd * VPAD;
      Vs[dd][cc] = V[(d0 + dd) * VPAD + cc];
    }
    __syncthreads();
    #pragma unroll
    for (int kk = 0; kk < BK; ++kk) {
      float xv[4], vv[5];
      #pragma unroll
      for (int ri = 0; ri < 4; ++ri) xv[ri] = Xs[ty + 8 * ri][kk];
      #pragma unroll
      for (int ci = 0; ci < 5; ++ci) vv[ci] = Vs[kk][tx + 32 * ci];
      #pragma unroll
      for (int ri = 0; ri < 4; ++ri)
        #pragma unroll
        for (int ci = 0; ci < 5; ++ci)
          acc[ri][ci] += xv[ri] * vv[ci];
    }
    __syncthreads();
  }
  #pragma unroll
  for (int ri = 0; ri < 4; ++ri)
    #pragma unroll
    for (int ci = 0; ci < 5; ++ci)
      Y[(row0 + ty + 8 * ri) * VPAD + tx + 32 * ci] = acc[ri][ci];
}

// ---------------- Q = Y^T Y  (144x144 incl. zero pad) ----------------
__global__ __launch_bounds__(256) void k_syrk(const float* __restrict__ Y,
                                              float* __restrict__ Q) {
  __shared__ float Ya[64][17];
  __shared__ float Yb[64][17];
  int bj = blockIdx.x * 16, bk = blockIdx.y * 16;
  int tid = threadIdx.x;
  int tj = tid & 15, tk = tid >> 4;
  float acc = 0.0f;
  for (int i0 = 0; i0 < NROWS; i0 += 64) {
    #pragma unroll
    for (int i = 0; i < 4; ++i) {
      int idx = tid + 256 * i;
      int r = idx >> 4, c = idx & 15;
      Ya[r][c] = Y[(i0 + r) * VPAD + bj + c];
      Yb[r][c] = Y[(i0 + r) * VPAD + bk + c];
    }
    __syncthreads();
    #pragma unroll
    for (int ii = 0; ii < 64; ++ii) acc += Ya[ii][tj] * Yb[ii][tk];
    __syncthreads();
  }
  Q[(bj + tj) * QS + bk + tk] = acc;
}

// ---------------- final: Cholesky(M), logdet, trace(M^-1 S), combine ----------------
__global__ __launch_bounds__(256) void k_final(const float* __restrict__ Mg,
                                               const float* __restrict__ Qg,
                                               const float* __restrict__ tvec,
                                               const float* __restrict__ mvec,
                                               const float* __restrict__ scalars,
                                               const int* __restrict__ fds,
                                               float* __restrict__ out) {
  __shared__ float L[KP][KP];
  __shared__ float Wb[KP][KP];
  __shared__ float tl[KP], ml[KP];
  int tid = threadIdx.x;
  for (int idx = tid; idx < KP * KP; idx += 256) {
    int r = idx / KP, c = idx - r * KP;
    L[r][c] = Mg[r * MS + c];
  }
  if (tid < KP) { tl[tid] = tvec[tid]; ml[tid] = mvec[tid]; }
  __syncthreads();

  // Cholesky (right-looking, in place, lower)
  float logdetM = 0.0f;
  for (int j = 0; j < KP; ++j) {
    if (tid == 0) {
      float v = sqrtf(L[j][j]);
      L[j][j] = v;
      logdetM += 2.0f * logf(v);
    }
    __syncthreads();
    float ljj = L[j][j];
    int r = j + 1 + tid;
    float lrj = 0.0f;
    if (r < KP) { lrj = L[r][j] / ljj; L[r][j] = lrj; }
    __syncthreads();
    if (r < KP) {
      for (int c = j + 1; c <= r; ++c) L[r][c] -= lrj * L[c][j];
    }
    __syncthreads();
  }

  // per-column: solve L w = S[:,c]; L^T u = w; accumulate u[c]
  float diag_u = 0.0f;
  if (tid < KP) {
    int c = tid;
    for (int r = 0; r < KP; ++r) {
      float s0 = 0.f, s1 = 0.f, s2 = 0.f, s3 = 0.f;
      int j = 0;
      for (; j + 3 < r; j += 4) {
        s0 += L[r][j    ] * Wb[j    ][c];
        s1 += L[r][j + 1] * Wb[j + 1][c];
        s2 += L[r][j + 2] * Wb[j + 2][c];
        s3 += L[r][j + 3] * Wb[j + 3][c];
      }
      for (; j < r; ++j) s0 += L[r][j] * Wb[j][c];
      float Sval = Qg[r * QS + c] - tl[r] * ml[c] - ml[r] * tl[c]
                 + (float)NROWS * ml[r] * ml[c];
      Wb[r][c] = (Sval - (s0 + s1) - (s2 + s3)) / L[r][r];
    }
    for (int r = KP - 1; r >= 0; --r) {
      float s0 = 0.f, s1 = 0.f, s2 = 0.f, s3 = 0.f;
      int j = r + 1;
      for (; j + 3 < KP; j += 4) {
        s0 += L[j    ][r] * Wb[j    ][c];
        s1 += L[j + 1][r] * Wb[j + 1][c];
        s2 += L[j + 2][r] * Wb[j + 2][c];
        s3 += L[j + 3][r] * Wb[j + 3][c];
      }
      for (; j < KP; ++j) s0 += L[j][r] * Wb[j][c];
      Wb[r][c] = (Wb[r][c] - (s0 + s1) - (s2 + s3)) / L[r][r];
    }
    diag_u = Wb[c][c];
  }
  float tr = blockReduceSum(tid < KP ? diag_u : 0.0f);
  if (tid == 0) {
    double sumlog = (double)scalars[0];
    double term1  = (double)scalars[1];
    double total = (double)NROWS * (double)D * LOG2PI
                 + (double)NROWS * (sumlog + (double)logdetM)
                 + term1 - (double)tr;
    double scale = (double)fds[0] / (double)NROWS;
    out[0] = (float)(scale * (-0.5) * total);
  }
}

// ---------------- launch ----------------
extern "C" void kernel_launch(void* const* d_in, const int* in_sizes, int n_in,
                              void* d_out, int out_size, void* d_ws, size_t ws_size,
                              hipStream_t stream) {
  const float* x     = (const float*)d_in[0];
  const float* theta = (const float*)d_in[1];
  const int*   fds   = (const int*)d_in[2];
  float* out = (float*)d_out;
  float* ws  = (float*)d_ws;

  // workspace layout (floats); total ~2.55M floats (~10.2 MB)
  float* V        = ws;                       // 4096*160
  float* VT       = V        + D * VPAD;      // 129*4096
  float* Y        = VT       + KP * D;        // 8192*160
  float* Q        = Y        + NROWS * VPAD;  // 144*144
  float* M        = Q        + QS * QS;       // 129*132
  float* colsum   = M        + KP * MS;       // 4096
  float* colsumsq = colsum   + D;             // 4096
  float* tvec     = colsumsq + D;             // 132
  float* mvec     = tvec     + MS;            // 132
  float* scalars  = mvec     + MS;            // 8

  // zero the atomic accumulators (+ small vecs, harmless)
  hipMemsetAsync(colsum, 0, (size_t)(2 * D + 2 * MS + 8) * sizeof(float), stream);

  k_prep     <<<dim3(D / 256), 256, 0, stream>>>(theta, V, VT);
  k_colstats <<<dim3(D / 256, NROWS / 256), 256, 0, stream>>>(x, colsum, colsumsq);
  k_M        <<<dim3(KP, KP), 256, 0, stream>>>(theta, VT, M);
  k_scalars  <<<dim3(1), 256, 0, stream>>>(theta, colsum, colsumsq, scalars);
  k_smallvecs<<<dim3(KP, 2), 256, 0, stream>>>(theta, VT, colsum, tvec, mvec);
  k_gemm     <<<dim3(NROWS / BM), 256, 0, stream>>>(x, V, Y);
  k_syrk     <<<dim3(QS / 16, QS / 16), 256, 0, stream>>>(Y, Q);
  k_final    <<<dim3(1), 256, 0, stream>>>(M, Q, tvec, mvec, scalars, fds, out);
}

// Round 2
// 804.017 us; speedup vs baseline: 2.1898x; 2.1898x over previous
//
#include <hip/hip_runtime.h>
#include <math.h>

#define D 4096
#define K 128
#define KP 129          // K+1 (augmented sqrt(EPS)*ones column)
#define VPAD 160        // padded column count for V / Y (zeros in pad)
#define NROWS 8192
#define QS 144          // Q row stride
#define MS 132          // M row stride
#define AS 132          // LDS stride for A in k_final (float4-friendly)
#define LOG2PI 1.8378770664093453

// ---------------- helpers ----------------
__device__ __forceinline__ float blockReduceSum(float v) {   // 256 threads
  #pragma unroll
  for (int off = 32; off > 0; off >>= 1) v += __shfl_down(v, off, 64);
  __shared__ float tmp[4];
  __syncthreads();
  if ((threadIdx.x & 63) == 0) tmp[threadIdx.x >> 6] = v;
  __syncthreads();
  float r = 0.0f;
  if (threadIdx.x == 0) r = tmp[0] + tmp[1] + tmp[2] + tmp[3];
  return r;                              // valid on tid 0 only
}

// ---------------- V and V^T: V[d][c] = U[d][c]/sigma[d] ----------------
__global__ __launch_bounds__(256) void k_prep(const float* __restrict__ theta,
                                              float* __restrict__ V,
                                              float* __restrict__ VT) {
  int d = blockIdx.x * 256 + threadIdx.x;
  if (d >= D) return;
  float invs = 1.0f / theta[D * K + D + d];      // 1/sigma[d]
  for (int c = 0; c < VPAD; ++c) {
    float v;
    if (c < K)       v = theta[d * K + c] * theta[D * K + 2 * D + c] * invs;
    else if (c == K) v = 1.0e-3f * invs;
    else             v = 0.0f;
    V[d * VPAD + c] = v;
    if (c < KP) VT[c * D + d] = v;
  }
}

// ---------------- column stats of x ----------------
__global__ __launch_bounds__(256) void k_colstats(const float* __restrict__ x,
                                                  float* __restrict__ colsum,
                                                  float* __restrict__ colsumsq) {
  int d = blockIdx.x * 256 + threadIdx.x;
  int i0 = blockIdx.y * 256;
  float s1 = 0.0f, s2 = 0.0f;
  for (int i = i0; i < i0 + 256; ++i) {
    float v = x[(size_t)i * D + d];
    s1 += v; s2 += v * v;
  }
  atomicAdd(&colsum[d], s1);
  atomicAdd(&colsumsq[d], s2);
}

// ---------------- M = I + V^T diag(sigma) V  (129x129) ----------------
__global__ __launch_bounds__(256) void k_M(const float* __restrict__ theta,
                                           const float* __restrict__ VT,
                                           float* __restrict__ M) {
  int j = blockIdx.x, k = blockIdx.y;
  if (k < j) return;                     // symmetry
  const float* sg = theta + D * K + D;
  float acc = 0.0f;
  for (int d = threadIdx.x; d < D; d += 256)
    acc += sg[d] * VT[j * D + d] * VT[k * D + d];
  float r = blockReduceSum(acc);
  if (threadIdx.x == 0) {
    float m = r + (j == k ? 1.0f : 0.0f);
    M[j * MS + k] = m;
    M[k * MS + j] = m;
  }
}

// ---------------- scalars: sum(log sigma), term1 ----------------
__global__ __launch_bounds__(256) void k_scalars(const float* __restrict__ theta,
                                                 const float* __restrict__ colsum,
                                                 const float* __restrict__ colsumsq,
                                                 float* __restrict__ scalars) {
  const float* mu = theta + D * K;
  const float* sg = theta + D * K + D;
  float a = 0.0f, b = 0.0f;
  for (int d = threadIdx.x; d < D; d += 256) {
    float s = sg[d];
    float m = mu[d];
    a += logf(s);
    b += (colsumsq[d] - 2.0f * m * colsum[d] + (float)NROWS * m * m) / s;
  }
  float ra = blockReduceSum(a);
  float rb = blockReduceSum(b);
  if (threadIdx.x == 0) { scalars[0] = ra; scalars[1] = rb; }
}

// ---------------- t = V^T colsum, m = V^T mu ----------------
__global__ __launch_bounds__(256) void k_smallvecs(const float* __restrict__ theta,
                                                   const float* __restrict__ VT,
                                                   const float* __restrict__ colsum,
                                                   float* __restrict__ tvec,
                                                   float* __restrict__ mvec) {
  int c = blockIdx.x;
  int which = blockIdx.y;
  const float* src = (which == 0) ? colsum : (theta + D * K);
  float a = 0.0f;
  for (int d = threadIdx.x; d < D; d += 256) a += VT[c * D + d] * src[d];
  float r = blockReduceSum(a);
  if (threadIdx.x == 0) { if (which == 0) tvec[c] = r; else mvec[c] = r; }
}

// ---------------- Y += X * V  (split-K, atomic epilogue) ----------------
#define GBM 64
#define GBK 32
#define KSPLIT 4
#define KCH (D / KSPLIT)   // 1024

__global__ __launch_bounds__(256) void k_gemm(const float* __restrict__ x,
                                              const float* __restrict__ V,
                                              float* __restrict__ Y) {
  __shared__ float Xs[GBK][68];          // transposed X tile, 16B-aligned rows
  __shared__ float Vs[GBK][VPAD];
  int row0 = blockIdx.x * GBM;
  int d0base = blockIdx.y * KCH;
  int tid = threadIdx.x;
  int tx = tid & 31, ty = tid >> 5;      // compute mapping: cols tx+32*ci, rows ty*8+ri
  int sr = tid >> 2, sk = (tid & 3) * 8; // staging: 4 threads cover 128B of one row
  float acc[8][5] = {};
  for (int dt = 0; dt < KCH; dt += GBK) {
    int d0 = d0base + dt;
    const float4 a0 = *reinterpret_cast<const float4*>(&x[(size_t)(row0 + sr) * D + d0 + sk]);
    const float4 a1 = *reinterpret_cast<const float4*>(&x[(size_t)(row0 + sr) * D + d0 + sk + 4]);
    Xs[sk + 0][sr] = a0.x; Xs[sk + 1][sr] = a0.y; Xs[sk + 2][sr] = a0.z; Xs[sk + 3][sr] = a0.w;
    Xs[sk + 4][sr] = a1.x; Xs[sk + 5][sr] = a1.y; Xs[sk + 6][sr] = a1.z; Xs[sk + 7][sr] = a1.w;
    #pragma unroll
    for (int i = 0; i < 20; ++i) {       // 32*160/256 = 20
      int idx = tid + 256 * i;
      int dd = idx / VPAD, cc = idx - dd * VPAD;
      Vs[dd][cc] = V[(size_t)(d0 + dd) * VPAD + cc];
    }
    __syncthreads();
    #pragma unroll 4
    for (int kk = 0; kk < GBK; ++kk) {
      float4 xa = *reinterpret_cast<const float4*>(&Xs[kk][ty * 8]);
      float4 xb = *reinterpret_cast<const float4*>(&Xs[kk][ty * 8 + 4]);
      float vv[5];
      #pragma unroll
      for (int ci = 0; ci < 5; ++ci) vv[ci] = Vs[kk][tx + 32 * ci];
      float xr[8] = {xa.x, xa.y, xa.z, xa.w, xb.x, xb.y, xb.z, xb.w};
      #pragma unroll
      for (int ri = 0; ri < 8; ++ri)
        #pragma unroll
        for (int ci = 0; ci < 5; ++ci)
          acc[ri][ci] += xr[ri] * vv[ci];
    }
    __syncthreads();
  }
  #pragma unroll
  for (int ri = 0; ri < 8; ++ri)
    #pragma unroll
    for (int ci = 0; ci < 5; ++ci)
      atomicAdd(&Y[(size_t)(row0 + ty * 8 + ri) * VPAD + tx + 32 * ci], acc[ri][ci]);
}

// ---------------- Q += Y^T Y  (row-split, atomic epilogue) ----------------
#define SYRK_ZSPLIT 4
__global__ __launch_bounds__(256) void k_syrk(const float* __restrict__ Y,
                                              float* __restrict__ Q) {
  __shared__ float Ya[64][17];
  __shared__ float Yb[64][17];
  int bj = blockIdx.x * 16, bk = blockIdx.y * 16;
  int i0base = blockIdx.z * (NROWS / SYRK_ZSPLIT);
  int tid = threadIdx.x;
  int tj = tid & 15, tk = tid >> 4;
  float acc = 0.0f;
  for (int i0 = i0base; i0 < i0base + NROWS / SYRK_ZSPLIT; i0 += 64) {
    #pragma unroll
    for (int i = 0; i < 4; ++i) {
      int idx = tid + 256 * i;
      int r = idx >> 4, c = idx & 15;
      Ya[r][c] = Y[(size_t)(i0 + r) * VPAD + bj + c];
      Yb[r][c] = Y[(size_t)(i0 + r) * VPAD + bk + c];
    }
    __syncthreads();
    #pragma unroll
    for (int ii = 0; ii < 64; ++ii) acc += Ya[ii][tj] * Yb[ii][tk];
    __syncthreads();
  }
  atomicAdd(&Q[(bj + tj) * QS + bk + tk], acc);
}

// ---------------- final: parallel Cholesky(M), logdet, trace(M^-1 S) ----------------
__global__ __launch_bounds__(512) void k_final(const float* __restrict__ Mg,
                                               const float* __restrict__ Qg,
                                               const float* __restrict__ tvec,
                                               const float* __restrict__ mvec,
                                               const float* __restrict__ scalars,
                                               const int* __restrict__ fds,
                                               float* __restrict__ out) {
  __shared__ float A[KP][AS];            // M, then L in lower triangle
  __shared__ float Wb[KP][KP];
  __shared__ float colv[AS];
  __shared__ float tl[KP], ml[KP], invd[KP];
  __shared__ float tmp8[8];
  int tid = threadIdx.x;

  // load M (zero the AS-pad columns)
  for (int idx = tid; idx < KP * AS; idx += 512) {
    int r = idx / AS, c = idx - r * AS;
    A[r][c] = (c < KP) ? Mg[r * MS + c] : 0.0f;
  }
  if (tid < KP) { tl[tid] = tvec[tid]; ml[tid] = mvec[tid]; }
  __syncthreads();

  // ---- Cholesky, right-looking, parallel float4 trailing update ----
  for (int j = 0; j < KP; ++j) {
    if (tid == 0) A[j][j] = sqrtf(A[j][j]);
    __syncthreads();
    float ljj = A[j][j];
    if (tid < AS) {
      float v = 0.0f;
      if (tid > j && tid < KP) {
        v = A[tid][j] / ljj;
        A[tid][j] = v;
      }
      colv[tid] = v;
    }
    __syncthreads();
    int nrow = KP - 1 - j;
    int total = nrow * (AS / 4);         // float4 units over rows j+1..128
    for (int t = tid; t < total; t += 512) {
      int rr = t / (AS / 4);
      int c4 = t - rr * (AS / 4);
      int r = j + 1 + rr;
      float4* Ar = reinterpret_cast<float4*>(&A[r][0]);
      float4 av = Ar[c4];
      float4 cv = *reinterpret_cast<const float4*>(&colv[c4 * 4]);
      float cr = colv[r];
      av.x -= cr * cv.x; av.y -= cr * cv.y; av.z -= cr * cv.z; av.w -= cr * cv.w;
      Ar[c4] = av;
    }
    __syncthreads();
  }

  // logdet(M) = 2*sum(log diag(L)); also invd
  {
    float lv = 0.0f;
    if (tid < KP) {
      float dv = A[tid][tid];
      invd[tid] = 1.0f / dv;
      lv = 2.0f * logf(dv);
    }
    #pragma unroll
    for (int off = 32; off > 0; off >>= 1) lv += __shfl_down(lv, off, 64);
    if ((tid & 63) == 0) tmp8[tid >> 6] = lv;
  }
  __syncthreads();
  float logdetM = 0.0f;
  if (tid == 0) {
    #pragma unroll
    for (int i = 0; i < 8; ++i) logdetM += tmp8[i];
  }
  __syncthreads();                        // tmp8 reused below

  // ---- per-column: solve L w = S[:,c]; L^T u = w; take u[c] ----
  float diag_u = 0.0f;
  if (tid < KP) {
    int c = tid;
    for (int r = 0; r < KP; ++r) {
      float s0 = 0.f, s1 = 0.f, s2 = 0.f, s3 = 0.f;
      int j = 0;
      for (; j + 3 < r; j += 4) {
        s0 += A[r][j    ] * Wb[j    ][c];
        s1 += A[r][j + 1] * Wb[j + 1][c];
        s2 += A[r][j + 2] * Wb[j + 2][c];
        s3 += A[r][j + 3] * Wb[j + 3][c];
      }
      for (; j < r; ++j) s0 += A[r][j] * Wb[j][c];
      float Sval = Qg[r * QS + c] - tl[r] * ml[c] - ml[r] * tl[c]
                 + (float)NROWS * ml[r] * ml[c];
      Wb[r][c] = (Sval - (s0 + s1) - (s2 + s3)) * invd[r];
    }
    for (int r = KP - 1; r >= 0; --r) {
      float s0 = 0.f, s1 = 0.f, s2 = 0.f, s3 = 0.f;
      int j = r + 1;
      for (; j + 3 < KP; j += 4) {
        s0 += A[j    ][r] * Wb[j    ][c];
        s1 += A[j + 1][r] * Wb[j + 1][c];
        s2 += A[j + 2][r] * Wb[j + 2][c];
        s3 += A[j + 3][r] * Wb[j + 3][c];
      }
      for (; j < KP; ++j) s0 += A[j][r] * Wb[j][c];
      Wb[r][c] = (Wb[r][c] - (s0 + s1) - (s2 + s3)) * invd[r];
    }
    diag_u = Wb[c][c];
  }
  // block reduce trace over 512 threads
  {
    float v = diag_u;
    #pragma unroll
    for (int off = 32; off > 0; off >>= 1) v += __shfl_down(v, off, 64);
    __syncthreads();
    if ((tid & 63) == 0) tmp8[tid >> 6] = v;
    __syncthreads();
    if (tid == 0) {
      float tr = 0.0f;
      #pragma unroll
      for (int i = 0; i < 8; ++i) tr += tmp8[i];
      double sumlog = (double)scalars[0];
      double term1  = (double)scalars[1];
      double total = (double)NROWS * (double)D * LOG2PI
                   + (double)NROWS * (sumlog + (double)logdetM)
                   + term1 - (double)tr;
      double scale = (double)fds[0] / (double)NROWS;
      out[0] = (float)(scale * (-0.5) * total);
    }
  }
}

// ---------------- launch ----------------
extern "C" void kernel_launch(void* const* d_in, const int* in_sizes, int n_in,
                              void* d_out, int out_size, void* d_ws, size_t ws_size,
                              hipStream_t stream) {
  const float* x     = (const float*)d_in[0];
  const float* theta = (const float*)d_in[1];
  const int*   fds   = (const int*)d_in[2];
  float* out = (float*)d_out;
  float* ws  = (float*)d_ws;

  // workspace layout (floats), atomically-accumulated buffers first (memset once)
  float* Y        = ws;                        // NROWS*VPAD = 1,310,720
  float* Q        = Y        + (size_t)NROWS * VPAD;  // QS*QS = 20,736
  float* colsum   = Q        + QS * QS;        // 4096
  float* colsumsq = colsum   + D;              // 4096
  float* V        = colsumsq + D;              // D*VPAD
  float* VT       = V        + (size_t)D * VPAD;      // KP*D
  float* M        = VT       + (size_t)KP * D;        // KP*MS
  float* tvec     = M        + KP * MS;
  float* mvec     = tvec     + MS;
  float* scalars  = mvec     + MS;

  size_t zero_floats = (size_t)NROWS * VPAD + QS * QS + 2 * D;
  hipMemsetAsync(Y, 0, zero_floats * sizeof(float), stream);

  k_prep     <<<dim3(D / 256), 256, 0, stream>>>(theta, V, VT);
  k_colstats <<<dim3(D / 256, NROWS / 256), 256, 0, stream>>>(x, colsum, colsumsq);
  k_M        <<<dim3(KP, KP), 256, 0, stream>>>(theta, VT, M);
  k_scalars  <<<dim3(1), 256, 0, stream>>>(theta, colsum, colsumsq, scalars);
  k_smallvecs<<<dim3(KP, 2), 256, 0, stream>>>(theta, VT, colsum, tvec, mvec);
  k_gemm     <<<dim3(NROWS / GBM, KSPLIT), 256, 0, stream>>>(x, V, Y);
  k_syrk     <<<dim3(QS / 16, QS / 16, SYRK_ZSPLIT), 256, 0, stream>>>(Y, Q);
  k_final    <<<dim3(1), 512, 0, stream>>>(M, Q, tvec, mvec, scalars, fds, out);
}

// Round 3
// 544.303 us; speedup vs baseline: 3.2347x; 1.4772x over previous
//
#include <hip/hip_runtime.h>
#include <math.h>

#define D 4096
#define K 128
#define KP 129          // K+1 (augmented sqrt(EPS)*ones column)
#define VPAD 160        // padded column count for V / Y (zeros in pad)
#define NROWS 8192
#define QS 144          // Q row stride
#define MS 132          // M row stride
#define NP 132          // padded order for k_final (M padded with identity)
#define NB 12           // panel width (11 panels)
#define LOG2PI 1.8378770664093453

// ---------------- helpers ----------------
__device__ __forceinline__ float blockReduceSum256(float v) {
  #pragma unroll
  for (int off = 32; off > 0; off >>= 1) v += __shfl_down(v, off, 64);
  __shared__ float tmp[4];
  __syncthreads();
  if ((threadIdx.x & 63) == 0) tmp[threadIdx.x >> 6] = v;
  __syncthreads();
  float r = 0.0f;
  if (threadIdx.x == 0) r = tmp[0] + tmp[1] + tmp[2] + tmp[3];
  return r;                              // valid on tid 0 only
}

// ---------------- V and V^T: V[d][c] = U[d][c]/sigma[d] ----------------
__global__ __launch_bounds__(256) void k_prep(const float* __restrict__ theta,
                                              float* __restrict__ V,
                                              float* __restrict__ VT) {
  int d = blockIdx.x * 256 + threadIdx.x;
  if (d >= D) return;
  float invs = 1.0f / theta[D * K + D + d];      // 1/sigma[d]
  for (int c = 0; c < VPAD; ++c) {
    float v;
    if (c < K)       v = theta[d * K + c] * theta[D * K + 2 * D + c] * invs;
    else if (c == K) v = 1.0e-3f * invs;
    else             v = 0.0f;
    V[(size_t)d * VPAD + c] = v;
    if (c < KP) VT[(size_t)c * D + d] = v;
  }
}

// ---------------- column stats of x (float4, runs after gemm: L3-warm) ----------------
__global__ __launch_bounds__(256) void k_colstats(const float* __restrict__ x,
                                                  float* __restrict__ colsum,
                                                  float* __restrict__ colsumsq) {
  int d4 = blockIdx.x * 256 + threadIdx.x;       // float4 column index, D/4=1024 total
  int i0 = blockIdx.y * (NROWS / 64);            // 128 rows per block
  float4 s1 = {0, 0, 0, 0}, s2 = {0, 0, 0, 0};
  for (int i = i0; i < i0 + NROWS / 64; ++i) {
    float4 v = *reinterpret_cast<const float4*>(&x[(size_t)i * D + d4 * 4]);
    s1.x += v.x; s1.y += v.y; s1.z += v.z; s1.w += v.w;
    s2.x += v.x * v.x; s2.y += v.y * v.y; s2.z += v.z * v.z; s2.w += v.w * v.w;
  }
  atomicAdd(&colsum[d4 * 4 + 0], s1.x); atomicAdd(&colsum[d4 * 4 + 1], s1.y);
  atomicAdd(&colsum[d4 * 4 + 2], s1.z); atomicAdd(&colsum[d4 * 4 + 3], s1.w);
  atomicAdd(&colsumsq[d4 * 4 + 0], s2.x); atomicAdd(&colsumsq[d4 * 4 + 1], s2.y);
  atomicAdd(&colsumsq[d4 * 4 + 2], s2.z); atomicAdd(&colsumsq[d4 * 4 + 3], s2.w);
}

// ---------------- M = I + V^T diag(sigma) V  (129x129) ----------------
__global__ __launch_bounds__(256) void k_M(const float* __restrict__ theta,
                                           const float* __restrict__ VT,
                                           float* __restrict__ M) {
  int j = blockIdx.x, k = blockIdx.y;
  if (k < j) return;                     // symmetry
  const float* sg = theta + D * K + D;
  float acc = 0.0f;
  for (int d = threadIdx.x; d < D; d += 256)
    acc += sg[d] * VT[(size_t)j * D + d] * VT[(size_t)k * D + d];
  float r = blockReduceSum256(acc);
  if (threadIdx.x == 0) {
    float m = r + (j == k ? 1.0f : 0.0f);
    M[j * MS + k] = m;
    M[k * MS + j] = m;
  }
}

// ---------------- scalars: sum(log sigma), term1 ----------------
__global__ __launch_bounds__(256) void k_scalars(const float* __restrict__ theta,
                                                 const float* __restrict__ colsum,
                                                 const float* __restrict__ colsumsq,
                                                 float* __restrict__ scalars) {
  const float* mu = theta + D * K;
  const float* sg = theta + D * K + D;
  float a = 0.0f, b = 0.0f;
  for (int d = threadIdx.x; d < D; d += 256) {
    float s = sg[d];
    float m = mu[d];
    a += logf(s);
    b += (colsumsq[d] - 2.0f * m * colsum[d] + (float)NROWS * m * m) / s;
  }
  float ra = blockReduceSum256(a);
  float rb = blockReduceSum256(b);
  if (threadIdx.x == 0) { scalars[0] = ra; scalars[1] = rb; }
}

// ---------------- t = V^T colsum, m = V^T mu ----------------
__global__ __launch_bounds__(256) void k_smallvecs(const float* __restrict__ theta,
                                                   const float* __restrict__ VT,
                                                   const float* __restrict__ colsum,
                                                   float* __restrict__ tvec,
                                                   float* __restrict__ mvec) {
  int c = blockIdx.x;
  int which = blockIdx.y;
  const float* src = (which == 0) ? colsum : (theta + D * K);
  float a = 0.0f;
  for (int d = threadIdx.x; d < D; d += 256) a += VT[(size_t)c * D + d] * src[d];
  float r = blockReduceSum256(a);
  if (threadIdx.x == 0) { if (which == 0) tvec[c] = r; else mvec[c] = r; }
}

// ---------------- Y += X * V  (8x5 register tile, split-K atomics) ----------------
#define GBM 64
#define GBK 32
#define KSPLIT 4
#define KCH (D / KSPLIT)   // 1024

__global__ __launch_bounds__(256) void k_gemm(const float* __restrict__ x,
                                              const float* __restrict__ V,
                                              float* __restrict__ Y) {
  __shared__ float Xs[GBK][72];          // transposed X tile; rows 16B-aligned
  __shared__ float Vs[GBK][VPAD];
  int row0 = blockIdx.x * GBM;
  int d0base = blockIdx.y * KCH;
  int tid = threadIdx.x;
  int tx = tid & 31, ty = tid >> 5;      // cols {tx*4+0..3, 128+tx}; rows ty*8+ri
  int sr = tid >> 2, sk = (tid & 3) * 8; // staging: 4 threads cover 128B of one row
  float acc[8][5] = {};
  for (int dt = 0; dt < KCH; dt += GBK) {
    int d0 = d0base + dt;
    const float4 a0 = *reinterpret_cast<const float4*>(&x[(size_t)(row0 + sr) * D + d0 + sk]);
    const float4 a1 = *reinterpret_cast<const float4*>(&x[(size_t)(row0 + sr) * D + d0 + sk + 4]);
    Xs[sk + 0][sr] = a0.x; Xs[sk + 1][sr] = a0.y; Xs[sk + 2][sr] = a0.z; Xs[sk + 3][sr] = a0.w;
    Xs[sk + 4][sr] = a1.x; Xs[sk + 5][sr] = a1.y; Xs[sk + 6][sr] = a1.z; Xs[sk + 7][sr] = a1.w;
    #pragma unroll
    for (int i = 0; i < 5; ++i) {        // 32*160/4 = 1280 float4s
      int f4 = tid + 256 * i;
      int dd = f4 / 40, c4 = f4 - dd * 40;
      *reinterpret_cast<float4*>(&Vs[dd][c4 * 4]) =
          *reinterpret_cast<const float4*>(&V[(size_t)(d0 + dd) * VPAD + c4 * 4]);
    }
    __syncthreads();
    #pragma unroll 2
    for (int kk = 0; kk < GBK; ++kk) {
      float4 xa = *reinterpret_cast<const float4*>(&Xs[kk][ty * 8]);
      float4 xb = *reinterpret_cast<const float4*>(&Xs[kk][ty * 8 + 4]);
      float4 v4 = *reinterpret_cast<const float4*>(&Vs[kk][tx * 4]);
      float v5 = Vs[kk][128 + tx];
      float xr[8] = {xa.x, xa.y, xa.z, xa.w, xb.x, xb.y, xb.z, xb.w};
      float vv[5] = {v4.x, v4.y, v4.z, v4.w, v5};
      #pragma unroll
      for (int ri = 0; ri < 8; ++ri)
        #pragma unroll
        for (int ci = 0; ci < 5; ++ci)
          acc[ri][ci] += xr[ri] * vv[ci];
    }
    __syncthreads();
  }
  #pragma unroll
  for (int ri = 0; ri < 8; ++ri) {
    size_t base = (size_t)(row0 + ty * 8 + ri) * VPAD;
    #pragma unroll
    for (int ci = 0; ci < 4; ++ci)
      atomicAdd(&Y[base + tx * 4 + ci], acc[ri][ci]);
    atomicAdd(&Y[base + 128 + tx], acc[ri][4]);
  }
}

// ---------------- Q += Y^T Y  (row-split, atomic epilogue) ----------------
#define SYRK_ZSPLIT 4
__global__ __launch_bounds__(256) void k_syrk(const float* __restrict__ Y,
                                              float* __restrict__ Q) {
  __shared__ float Ya[64][17];
  __shared__ float Yb[64][17];
  int bj = blockIdx.x * 16, bk = blockIdx.y * 16;
  int i0base = blockIdx.z * (NROWS / SYRK_ZSPLIT);
  int tid = threadIdx.x;
  int tj = tid & 15, tk = tid >> 4;
  float acc = 0.0f;
  for (int i0 = i0base; i0 < i0base + NROWS / SYRK_ZSPLIT; i0 += 64) {
    #pragma unroll
    for (int i = 0; i < 4; ++i) {
      int idx = tid + 256 * i;
      int r = idx >> 4, c = idx & 15;
      Ya[r][c] = Y[(size_t)(i0 + r) * VPAD + bj + c];
      Yb[r][c] = Y[(size_t)(i0 + r) * VPAD + bk + c];
    }
    __syncthreads();
    #pragma unroll
    for (int ii = 0; ii < 64; ++ii) acc += Ya[ii][tj] * Yb[ii][tk];
    __syncthreads();
  }
  atomicAdd(&Q[(bj + tj) * QS + bk + tk], acc);
}

// ---------------- final: blocked Cholesky + blocked solves + trace ----------------
__global__ __launch_bounds__(512) void k_final(const float* __restrict__ Mg,
                                               const float* __restrict__ Qg,
                                               const float* __restrict__ tvec,
                                               const float* __restrict__ mvec,
                                               const float* __restrict__ scalars,
                                               const int* __restrict__ fds,
                                               float* __restrict__ out) {
  __shared__ float A[NP][NP];            // M (identity-padded) -> L (lower)
  __shared__ float Wm[NP][NP];           // S -> M^-1 S
  __shared__ float invd[NP];
  __shared__ float tl[NP], ml[NP];
  __shared__ float redA[8], redB[8];
  int tid = threadIdx.x;

  if (tid < NP) {
    tl[tid] = (tid < KP) ? tvec[tid] : 0.0f;
    ml[tid] = (tid < KP) ? mvec[tid] : 0.0f;
  }
  for (int idx = tid; idx < NP * NP; idx += 512) {
    int r = idx / NP, c = idx - r * NP;
    A[r][c] = (r < KP && c < KP) ? Mg[r * MS + c] : (r == c ? 1.0f : 0.0f);
  }
  __syncthreads();
  for (int idx = tid; idx < NP * NP; idx += 512) {
    int r = idx / NP, c = idx - r * NP;
    float s = 0.0f;
    if (r < KP && c < KP)
      s = Qg[r * QS + c] - tl[r] * ml[c] - ml[r] * tl[c] + (float)NROWS * ml[r] * ml[c];
    Wm[r][c] = s;
  }
  float logsum = 0.0f;                   // per-lane logdet contributions (wave 0, lanes<NB)
  __syncthreads();

  // ======== blocked Cholesky ========
  for (int p = 0; p < NP / NB; ++p) {
    int j0 = p * NB, j1 = j0 + NB;
    // (1) 12x12 diag Cholesky in wave-0 registers (no barriers inside)
    if (tid < 64) {
      int r = tid;
      int rr = (r < NB) ? r : 0;
      const float* arow = &A[j0 + rr][j0];
      float4 q0 = *reinterpret_cast<const float4*>(arow);
      float4 q1 = *reinterpret_cast<const float4*>(arow + 4);
      float4 q2 = *reinterpret_cast<const float4*>(arow + 8);
      float row[NB] = {q0.x, q0.y, q0.z, q0.w, q1.x, q1.y, q1.z, q1.w,
                       q2.x, q2.y, q2.z, q2.w};
      float mydiag = 1.0f;
      #pragma unroll
      for (int jj = 0; jj < NB; ++jj) {
        float s = sqrtf(__shfl(row[jj], jj));
        if (r == jj) { logsum += 2.0f * logf(s); mydiag = s; row[jj] = s; }
        else if (r > jj) row[jj] /= s;
        #pragma unroll
        for (int cc = jj + 1; cc < NB; ++cc) {
          float lc = __shfl(row[jj], cc);
          if (r > jj) row[cc] -= row[jj] * lc;
        }
      }
      if (r < NB) {
        float* wrow = &A[j0 + r][j0];
        #pragma unroll
        for (int k = 0; k < NB; ++k) if (k <= r) wrow[k] = row[k];
        invd[j0 + r] = 1.0f / mydiag;
      }
    }
    __syncthreads();
    // (2) panel solve: rows r in [j1, NP), one row per thread
    int nbrows = NP - j1;
    if (tid < nbrows) {
      int r = j1 + tid;
      float* arow = &A[r][j0];
      float4 q0 = *reinterpret_cast<const float4*>(arow);
      float4 q1 = *reinterpret_cast<const float4*>(arow + 4);
      float4 q2 = *reinterpret_cast<const float4*>(arow + 8);
      float row[NB] = {q0.x, q0.y, q0.z, q0.w, q1.x, q1.y, q1.z, q1.w,
                       q2.x, q2.y, q2.z, q2.w};
      #pragma unroll
      for (int cc = 0; cc < NB; ++cc) {
        float a2 = row[cc];
        #pragma unroll
        for (int k = 0; k < NB; ++k) if (k < cc) a2 -= row[k] * A[j0 + cc][j0 + k];
        row[cc] = a2 * invd[j0 + cc];
      }
      float4 w0 = {row[0], row[1], row[2], row[3]};
      float4 w1 = {row[4], row[5], row[6], row[7]};
      float4 w2 = {row[8], row[9], row[10], row[11]};
      *reinterpret_cast<float4*>(arow) = w0;
      *reinterpret_cast<float4*>(arow + 4) = w1;
      *reinterpret_cast<float4*>(arow + 8) = w2;
    }
    __syncthreads();
    // (3) trailing syrk update, lower blocks only, 4x4 tasks
    int nt4 = nbrows / 4;
    for (int t = tid; t < nt4 * nt4; t += 512) {
      int r4 = t / nt4, c4 = t - r4 * nt4;
      if (c4 > r4) continue;
      int r = j1 + r4 * 4, c = j1 + c4 * 4;
      float4 a0 = *reinterpret_cast<float4*>(&A[r + 0][c]);
      float4 a1 = *reinterpret_cast<float4*>(&A[r + 1][c]);
      float4 a2 = *reinterpret_cast<float4*>(&A[r + 2][c]);
      float4 a3 = *reinterpret_cast<float4*>(&A[r + 3][c]);
      #pragma unroll
      for (int k = 0; k < NB; ++k) {
        float pc0 = A[c + 0][j0 + k], pc1 = A[c + 1][j0 + k];
        float pc2 = A[c + 2][j0 + k], pc3 = A[c + 3][j0 + k];
        float pr0 = A[r + 0][j0 + k], pr1 = A[r + 1][j0 + k];
        float pr2 = A[r + 2][j0 + k], pr3 = A[r + 3][j0 + k];
        a0.x -= pr0 * pc0; a0.y -= pr0 * pc1; a0.z -= pr0 * pc2; a0.w -= pr0 * pc3;
        a1.x -= pr1 * pc0; a1.y -= pr1 * pc1; a1.z -= pr1 * pc2; a1.w -= pr1 * pc3;
        a2.x -= pr2 * pc0; a2.y -= pr2 * pc1; a2.z -= pr2 * pc2; a2.w -= pr2 * pc3;
        a3.x -= pr3 * pc0; a3.y -= pr3 * pc1; a3.z -= pr3 * pc2; a3.w -= pr3 * pc3;
      }
      *reinterpret_cast<float4*>(&A[r + 0][c]) = a0;
      *reinterpret_cast<float4*>(&A[r + 1][c]) = a1;
      *reinterpret_cast<float4*>(&A[r + 2][c]) = a2;
      *reinterpret_cast<float4*>(&A[r + 3][c]) = a3;
    }
    __syncthreads();
  }

  // ======== forward solve: L W = S ========
  for (int p = 0; p < NP / NB; ++p) {
    int j0 = p * NB, j1 = j0 + NB;
    if (tid < NP) {
      int c = tid;
      float w[NB];
      #pragma unroll
      for (int k = 0; k < NB; ++k) w[k] = Wm[j0 + k][c];
      #pragma unroll
      for (int kk = 0; kk < NB; ++kk) {
        float a2 = w[kk];
        #pragma unroll
        for (int k = 0; k < NB; ++k) if (k < kk) a2 -= A[j0 + kk][j0 + k] * w[k];
        w[kk] = a2 * invd[j0 + kk];
      }
      #pragma unroll
      for (int k = 0; k < NB; ++k) Wm[j0 + k][c] = w[k];
    }
    __syncthreads();
    int nbrows = NP - j1;
    int nr4 = nbrows / 4, nc4 = NP / 4;
    for (int t = tid; t < nr4 * nc4; t += 512) {
      int r4 = t / nc4, c4 = t - r4 * nc4;
      int r = j1 + r4 * 4, c = c4 * 4;
      float4 a0 = *reinterpret_cast<float4*>(&Wm[r + 0][c]);
      float4 a1 = *reinterpret_cast<float4*>(&Wm[r + 1][c]);
      float4 a2 = *reinterpret_cast<float4*>(&Wm[r + 2][c]);
      float4 a3 = *reinterpret_cast<float4*>(&Wm[r + 3][c]);
      #pragma unroll
      for (int k = 0; k < NB; ++k) {
        float l0 = A[r + 0][j0 + k], l1 = A[r + 1][j0 + k];
        float l2 = A[r + 2][j0 + k], l3 = A[r + 3][j0 + k];
        float4 wr = *reinterpret_cast<const float4*>(&Wm[j0 + k][c]);
        a0.x -= l0 * wr.x; a0.y -= l0 * wr.y; a0.z -= l0 * wr.z; a0.w -= l0 * wr.w;
        a1.x -= l1 * wr.x; a1.y -= l1 * wr.y; a1.z -= l1 * wr.z; a1.w -= l1 * wr.w;
        a2.x -= l2 * wr.x; a2.y -= l2 * wr.y; a2.z -= l2 * wr.z; a2.w -= l2 * wr.w;
        a3.x -= l3 * wr.x; a3.y -= l3 * wr.y; a3.z -= l3 * wr.z; a3.w -= l3 * wr.w;
      }
      *reinterpret_cast<float4*>(&Wm[r + 0][c]) = a0;
      *reinterpret_cast<float4*>(&Wm[r + 1][c]) = a1;
      *reinterpret_cast<float4*>(&Wm[r + 2][c]) = a2;
      *reinterpret_cast<float4*>(&Wm[r + 3][c]) = a3;
    }
    __syncthreads();
  }

  // ======== backward solve: L^T U = W ========
  for (int p = NP / NB - 1; p >= 0; --p) {
    int j0 = p * NB;
    if (tid < NP) {
      int c = tid;
      float w[NB];
      #pragma unroll
      for (int k = 0; k < NB; ++k) w[k] = Wm[j0 + k][c];
      #pragma unroll
      for (int kk = NB - 1; kk >= 0; --kk) {
        float a2 = w[kk];
        #pragma unroll
        for (int k = 0; k < NB; ++k) if (k > kk) a2 -= A[j0 + k][j0 + kk] * w[k];
        w[kk] = a2 * invd[j0 + kk];
      }
      #pragma unroll
      for (int k = 0; k < NB; ++k) Wm[j0 + k][c] = w[k];
    }
    __syncthreads();
    int nr4 = j0 / 4, nc4 = NP / 4;
    for (int t = tid; t < nr4 * nc4; t += 512) {
      int r4 = t / nc4, c4 = t - r4 * nc4;
      int r = r4 * 4, c = c4 * 4;
      float4 a0 = *reinterpret_cast<float4*>(&Wm[r + 0][c]);
      float4 a1 = *reinterpret_cast<float4*>(&Wm[r + 1][c]);
      float4 a2 = *reinterpret_cast<float4*>(&Wm[r + 2][c]);
      float4 a3 = *reinterpret_cast<float4*>(&Wm[r + 3][c]);
      #pragma unroll
      for (int k = 0; k < NB; ++k) {
        float l0 = A[j0 + k][r + 0], l1 = A[j0 + k][r + 1];
        float l2 = A[j0 + k][r + 2], l3 = A[j0 + k][r + 3];
        float4 wr = *reinterpret_cast<const float4*>(&Wm[j0 + k][c]);
        a0.x -= l0 * wr.x; a0.y -= l0 * wr.y; a0.z -= l0 * wr.z; a0.w -= l0 * wr.w;
        a1.x -= l1 * wr.x; a1.y -= l1 * wr.y; a1.z -= l1 * wr.z; a1.w -= l1 * wr.w;
        a2.x -= l2 * wr.x; a2.y -= l2 * wr.y; a2.z -= l2 * wr.z; a2.w -= l2 * wr.w;
        a3.x -= l3 * wr.x; a3.y -= l3 * wr.y; a3.z -= l3 * wr.z; a3.w -= l3 * wr.w;
      }
      *reinterpret_cast<float4*>(&Wm[r + 0][c]) = a0;
      *reinterpret_cast<float4*>(&Wm[r + 1][c]) = a1;
      *reinterpret_cast<float4*>(&Wm[r + 2][c]) = a2;
      *reinterpret_cast<float4*>(&Wm[r + 3][c]) = a3;
    }
    __syncthreads();
  }

  // ======== trace + logdet + combine ========
  float dv = (tid < KP) ? Wm[tid][tid] : 0.0f;
  float v1 = dv, v2 = logsum;
  #pragma unroll
  for (int off = 32; off > 0; off >>= 1) {
    v1 += __shfl_down(v1, off, 64);
    v2 += __shfl_down(v2, off, 64);
  }
  if ((tid & 63) == 0) { redA[tid >> 6] = v1; redB[tid >> 6] = v2; }
  __syncthreads();
  if (tid == 0) {
    float tr = 0.0f, logdetM = 0.0f;
    #pragma unroll
    for (int i = 0; i < 8; ++i) { tr += redA[i]; logdetM += redB[i]; }
    double sumlog = (double)scalars[0];
    double term1  = (double)scalars[1];
    double total = (double)NROWS * (double)D * LOG2PI
                 + (double)NROWS * (sumlog + (double)logdetM)
                 + term1 - (double)tr;
    double scale = (double)fds[0] / (double)NROWS;
    out[0] = (float)(scale * (-0.5) * total);
  }
}

// ---------------- launch ----------------
extern "C" void kernel_launch(void* const* d_in, const int* in_sizes, int n_in,
                              void* d_out, int out_size, void* d_ws, size_t ws_size,
                              hipStream_t stream) {
  const float* x     = (const float*)d_in[0];
  const float* theta = (const float*)d_in[1];
  const int*   fds   = (const int*)d_in[2];
  float* out = (float*)d_out;
  float* ws  = (float*)d_ws;

  float* Y        = ws;                               // NROWS*VPAD
  float* Q        = Y        + (size_t)NROWS * VPAD;  // QS*QS
  float* colsum   = Q        + QS * QS;               // D
  float* colsumsq = colsum   + D;                     // D
  float* V        = colsumsq + D;                     // D*VPAD
  float* VT       = V        + (size_t)D * VPAD;      // KP*D
  float* M        = VT       + (size_t)KP * D;        // KP*MS
  float* tvec     = M        + KP * MS;
  float* mvec     = tvec     + MS;
  float* scalars  = mvec     + MS;

  size_t zero_floats = (size_t)NROWS * VPAD + QS * QS + 2 * D;
  hipMemsetAsync(Y, 0, zero_floats * sizeof(float), stream);

  k_prep     <<<dim3(D / 256), 256, 0, stream>>>(theta, V, VT);
  k_gemm     <<<dim3(NROWS / GBM, KSPLIT), 256, 0, stream>>>(x, V, Y);
  k_colstats <<<dim3(D / 4 / 256, 64), 256, 0, stream>>>(x, colsum, colsumsq);
  k_M        <<<dim3(KP, KP), 256, 0, stream>>>(theta, VT, M);
  k_scalars  <<<dim3(1), 256, 0, stream>>>(theta, colsum, colsumsq, scalars);
  k_smallvecs<<<dim3(KP, 2), 256, 0, stream>>>(theta, VT, colsum, tvec, mvec);
  k_syrk     <<<dim3(QS / 16, QS / 16, SYRK_ZSPLIT), 256, 0, stream>>>(Y, Q);
  k_final    <<<dim3(1), 512, 0, stream>>>(M, Q, tvec, mvec, scalars, fds, out);
}

// Round 4
// 287.380 us; speedup vs baseline: 6.1265x; 1.8940x over previous
//
#include <hip/hip_runtime.h>
#include <math.h>

#define D 4096
#define K 128
#define KP 129          // K+1 (augmented sqrt(EPS)*ones column)
#define NC 144          // padded col count for VbT / Yb (9 tiles of 16; cols >= 129 zero)
#define NROWS 8192
#define QS 144          // Q row stride
#define MS 132          // M row stride
#define NP 132          // padded order for k_final
#define NB 12           // k_final panel width
#define LOG2PI 1.8378770664093453

typedef __attribute__((ext_vector_type(8))) short bh8;     // 8 bf16 (4 VGPRs)
typedef __attribute__((ext_vector_type(4))) float f32x4;   // MFMA acc

// ---------------- helpers ----------------
__device__ __forceinline__ unsigned short f2bf(float f) {  // RNE
  unsigned int u = __float_as_uint(f);
  unsigned int r = u + 0x7FFFu + ((u >> 16) & 1u);
  return (unsigned short)(r >> 16);
}
__device__ __forceinline__ float bf2f(unsigned short u) {
  return __uint_as_float(((unsigned int)u) << 16);
}
__device__ __forceinline__ float blo(unsigned int v) { return __uint_as_float(v << 16); }
__device__ __forceinline__ float bhi(unsigned int v) { return __uint_as_float(v & 0xFFFF0000u); }

__device__ __forceinline__ float blockReduceSum256(float v) {
  #pragma unroll
  for (int off = 32; off > 0; off >>= 1) v += __shfl_down(v, off, 64);
  __shared__ float tmp[4];
  __syncthreads();
  if ((threadIdx.x & 63) == 0) tmp[threadIdx.x >> 6] = v;
  __syncthreads();
  float r = 0.0f;
  if (threadIdx.x == 0) r = tmp[0] + tmp[1] + tmp[2] + tmp[3];
  return r;                              // valid on tid 0 only
}

// ---------------- VbT[c][d] = bf16( U[d][c] / sigma[d] ), rows c>=129 zero ----------------
__global__ __launch_bounds__(256) void k_prep(const float* __restrict__ theta,
                                              unsigned short* __restrict__ VbT) {
  int c = blockIdx.x;                    // 0..143
  const float* sg = theta + (size_t)D * K + D;
  float al = (c < K) ? theta[(size_t)D * K + 2 * D + c] : 0.0f;
  for (int d = threadIdx.x; d < D; d += 256) {
    float v;
    if (c < K)       v = theta[(size_t)d * K + c] * al / sg[d];
    else if (c == K) v = 1.0e-3f / sg[d];
    else             v = 0.0f;
    VbT[(size_t)c * D + d] = f2bf(v);
  }
}

// ---------------- column stats of x (fp32 exact) ----------------
__global__ __launch_bounds__(256) void k_colstats(const float* __restrict__ x,
                                                  float* __restrict__ colsum,
                                                  float* __restrict__ colsumsq) {
  int d4 = blockIdx.x * 256 + threadIdx.x;       // float4 column index
  int i0 = blockIdx.y * (NROWS / 64);
  float4 s1 = {0, 0, 0, 0}, s2 = {0, 0, 0, 0};
  for (int i = i0; i < i0 + NROWS / 64; ++i) {
    float4 v = *reinterpret_cast<const float4*>(&x[(size_t)i * D + d4 * 4]);
    s1.x += v.x; s1.y += v.y; s1.z += v.z; s1.w += v.w;
    s2.x += v.x * v.x; s2.y += v.y * v.y; s2.z += v.z * v.z; s2.w += v.w * v.w;
  }
  atomicAdd(&colsum[d4 * 4 + 0], s1.x); atomicAdd(&colsum[d4 * 4 + 1], s1.y);
  atomicAdd(&colsum[d4 * 4 + 2], s1.z); atomicAdd(&colsum[d4 * 4 + 3], s1.w);
  atomicAdd(&colsumsq[d4 * 4 + 0], s2.x); atomicAdd(&colsumsq[d4 * 4 + 1], s2.y);
  atomicAdd(&colsumsq[d4 * 4 + 2], s2.z); atomicAdd(&colsumsq[d4 * 4 + 3], s2.w);
}

// ---------------- M = I + sum_d sigma_d VbT[j][d] VbT[k][d] ----------------
__global__ __launch_bounds__(256) void k_M(const float* __restrict__ theta,
                                           const unsigned short* __restrict__ VbT,
                                           float* __restrict__ M) {
  int j = blockIdx.x, kk2 = blockIdx.y;
  if (kk2 < j) return;                   // symmetry
  const float* sg = theta + (size_t)D * K + D;
  float acc = 0.0f;
  for (int d0 = threadIdx.x * 8; d0 < D; d0 += 2048) {
    uint4 ua = *reinterpret_cast<const uint4*>(&VbT[(size_t)j * D + d0]);
    uint4 ub = *reinterpret_cast<const uint4*>(&VbT[(size_t)kk2 * D + d0]);
    float4 s0 = *reinterpret_cast<const float4*>(&sg[d0]);
    float4 s1 = *reinterpret_cast<const float4*>(&sg[d0 + 4]);
    acc += s0.x * blo(ua.x) * blo(ub.x) + s0.y * bhi(ua.x) * bhi(ub.x)
         + s0.z * blo(ua.y) * blo(ub.y) + s0.w * bhi(ua.y) * bhi(ub.y)
         + s1.x * blo(ua.z) * blo(ub.z) + s1.y * bhi(ua.z) * bhi(ub.z)
         + s1.z * blo(ua.w) * blo(ub.w) + s1.w * bhi(ua.w) * bhi(ub.w);
  }
  float r = blockReduceSum256(acc);
  if (threadIdx.x == 0) {
    float m = r + (j == kk2 ? 1.0f : 0.0f);
    M[j * MS + kk2] = m;
    M[kk2 * MS + j] = m;
  }
}

// ---------------- scalars: sum(log sigma), term1 ----------------
__global__ __launch_bounds__(256) void k_scalars(const float* __restrict__ theta,
                                                 const float* __restrict__ colsum,
                                                 const float* __restrict__ colsumsq,
                                                 float* __restrict__ scalars) {
  const float* mu = theta + (size_t)D * K;
  const float* sg = theta + (size_t)D * K + D;
  float a = 0.0f, b = 0.0f;
  for (int d = threadIdx.x; d < D; d += 256) {
    float s = sg[d];
    float m = mu[d];
    a += logf(s);
    b += (colsumsq[d] - 2.0f * m * colsum[d] + (float)NROWS * m * m) / s;
  }
  float ra = blockReduceSum256(a);
  float rb = blockReduceSum256(b);
  if (threadIdx.x == 0) { scalars[0] = ra; scalars[1] = rb; }
}

// ---------------- t = V^T colsum, m = V^T mu (from bf16 VbT) ----------------
__global__ __launch_bounds__(256) void k_smallvecs(const float* __restrict__ theta,
                                                   const unsigned short* __restrict__ VbT,
                                                   const float* __restrict__ colsum,
                                                   float* __restrict__ tvec,
                                                   float* __restrict__ mvec) {
  int c = blockIdx.x;
  int which = blockIdx.y;
  const float* src = (which == 0) ? colsum : (theta + (size_t)D * K);
  float a = 0.0f;
  for (int d = threadIdx.x; d < D; d += 256) a += bf2f(VbT[(size_t)c * D + d]) * src[d];
  float r = blockReduceSum256(a);
  if (threadIdx.x == 0) { if (which == 0) tvec[c] = r; else mvec[c] = r; }
}

// ---------------- Yb = bf16( X * V )  via MFMA 16x16x32 ----------------
#define GBM 32
#define GBK 128
#define NSTEP (D / GBK)     // 32
#define XSS 136             // LDS row stride in shorts (GBK+8): bank stride 4 -> 2-way max

__global__ __launch_bounds__(512) void k_gemm(const float* __restrict__ x,
                                              const unsigned short* __restrict__ VbT,
                                              unsigned short* __restrict__ Yb) {
  __shared__ unsigned short Xs[GBM][XSS];   // bf16 X tile
  __shared__ unsigned short Vs[NC][XSS];    // bf16 V^T tile
  int tid = threadIdx.x;
  int row0 = blockIdx.x * GBM;
  int wid = tid >> 6, lane = tid & 63;
  int lr = lane & 15, lk = (lane >> 4) * 8;
  int rt = wid & 1;                         // row tile (16 rows)
  int cg = wid >> 1;                        // col group
  int ct0 = (cg == 0) ? 0 : (cg * 2 + 1);   // col tiles: {0,1,2},{3,4},{5,6},{7,8}
  int nct = (cg == 0) ? 3 : 2;

  // staging maps
  int sxr = tid >> 4;                       // X: row 0..31
  int sxk = (tid & 15) * 8;                 // X: k-octet
  int vrb = tid >> 4;                       // V: base row (+32 per j)
  int vk  = (tid & 15) * 8;

  float4 xr0, xr1;
  uint4 vr0, vr1, vr2, vr3, vr4;

  // prologue: load tile 0
  {
    const float* xb = &x[(size_t)(row0 + sxr) * D + sxk];
    xr0 = *reinterpret_cast<const float4*>(xb);
    xr1 = *reinterpret_cast<const float4*>(xb + 4);
    const unsigned short* vb = &VbT[(size_t)vrb * D + vk];
    vr0 = *reinterpret_cast<const uint4*>(vb);
    vr1 = *reinterpret_cast<const uint4*>(vb + (size_t)32 * D);
    vr2 = *reinterpret_cast<const uint4*>(vb + (size_t)64 * D);
    vr3 = *reinterpret_cast<const uint4*>(vb + (size_t)96 * D);
    if (tid < 256) vr4 = *reinterpret_cast<const uint4*>(vb + (size_t)128 * D);
  }

  f32x4 acc0 = {0, 0, 0, 0}, acc1 = {0, 0, 0, 0}, acc2 = {0, 0, 0, 0};

  for (int s = 0; s < NSTEP; ++s) {
    // write staged regs -> LDS (convert X to bf16)
    {
      uint4 w;
      w.x = (unsigned)f2bf(xr0.x) | ((unsigned)f2bf(xr0.y) << 16);
      w.y = (unsigned)f2bf(xr0.z) | ((unsigned)f2bf(xr0.w) << 16);
      w.z = (unsigned)f2bf(xr1.x) | ((unsigned)f2bf(xr1.y) << 16);
      w.w = (unsigned)f2bf(xr1.z) | ((unsigned)f2bf(xr1.w) << 16);
      *reinterpret_cast<uint4*>(&Xs[sxr][sxk]) = w;
      unsigned short* vd = &Vs[vrb][vk];
      *reinterpret_cast<uint4*>(vd) = vr0;
      *reinterpret_cast<uint4*>(vd + 32 * XSS) = vr1;
      *reinterpret_cast<uint4*>(vd + 64 * XSS) = vr2;
      *reinterpret_cast<uint4*>(vd + 96 * XSS) = vr3;
      if (tid < 256) *reinterpret_cast<uint4*>(vd + 128 * XSS) = vr4;
    }
    __syncthreads();
    // prefetch next tile under compute
    if (s + 1 < NSTEP) {
      const float* xb = &x[(size_t)(row0 + sxr) * D + (s + 1) * GBK + sxk];
      xr0 = *reinterpret_cast<const float4*>(xb);
      xr1 = *reinterpret_cast<const float4*>(xb + 4);
      const unsigned short* vb = &VbT[(size_t)vrb * D + (s + 1) * GBK + vk];
      vr0 = *reinterpret_cast<const uint4*>(vb);
      vr1 = *reinterpret_cast<const uint4*>(vb + (size_t)32 * D);
      vr2 = *reinterpret_cast<const uint4*>(vb + (size_t)64 * D);
      vr3 = *reinterpret_cast<const uint4*>(vb + (size_t)96 * D);
      if (tid < 256) vr4 = *reinterpret_cast<const uint4*>(vb + (size_t)128 * D);
    }
    #pragma unroll
    for (int ks = 0; ks < 4; ++ks) {
      bh8 a = *reinterpret_cast<const bh8*>(&Xs[rt * 16 + lr][ks * 32 + lk]);
      bh8 b0 = *reinterpret_cast<const bh8*>(&Vs[ct0 * 16 + lr][ks * 32 + lk]);
      acc0 = __builtin_amdgcn_mfma_f32_16x16x32_bf16(a, b0, acc0, 0, 0, 0);
      bh8 b1 = *reinterpret_cast<const bh8*>(&Vs[(ct0 + 1) * 16 + lr][ks * 32 + lk]);
      acc1 = __builtin_amdgcn_mfma_f32_16x16x32_bf16(a, b1, acc1, 0, 0, 0);
      if (nct == 3) {
        bh8 b2 = *reinterpret_cast<const bh8*>(&Vs[(ct0 + 2) * 16 + lr][ks * 32 + lk]);
        acc2 = __builtin_amdgcn_mfma_f32_16x16x32_bf16(a, b2, acc2, 0, 0, 0);
      }
    }
    __syncthreads();
  }

  // epilogue: C/D layout col = lane&15, row = (lane>>4)*4 + reg  [m89/m91 verified]
  int rw = row0 + rt * 16 + ((lane >> 4) << 2);
  #pragma unroll
  for (int g = 0; g < 4; ++g)
    Yb[(size_t)(rw + g) * NC + ct0 * 16 + lr] = f2bf(acc0[g]);
  #pragma unroll
  for (int g = 0; g < 4; ++g)
    Yb[(size_t)(rw + g) * NC + (ct0 + 1) * 16 + lr] = f2bf(acc1[g]);
  if (nct == 3) {
    #pragma unroll
    for (int g = 0; g < 4; ++g)
      Yb[(size_t)(rw + g) * NC + (ct0 + 2) * 16 + lr] = f2bf(acc2[g]);
  }
}

// ---------------- Q += Yb^T Yb  (bf16 in, symmetry, row-split atomics) ----------------
#define SYRK_ZSPLIT 4
__global__ __launch_bounds__(256) void k_syrk(const unsigned short* __restrict__ Yb,
                                              float* __restrict__ Q) {
  int bj = blockIdx.x * 16, bk = blockIdx.y * 16;
  if (bk < bj) return;                   // symmetry
  __shared__ float Ya[64][17];
  __shared__ float Yc[64][17];
  int i0base = blockIdx.z * (NROWS / SYRK_ZSPLIT);
  int tid = threadIdx.x;
  int tj = tid & 15, tk = tid >> 4;
  int lr = tid >> 2, lc = (tid & 3) * 4;
  float acc = 0.0f;
  for (int i0 = i0base; i0 < i0base + NROWS / SYRK_ZSPLIT; i0 += 64) {
    ushort4 va = *reinterpret_cast<const ushort4*>(&Yb[(size_t)(i0 + lr) * NC + bj + lc]);
    ushort4 vc = *reinterpret_cast<const ushort4*>(&Yb[(size_t)(i0 + lr) * NC + bk + lc]);
    Ya[lr][lc + 0] = bf2f(va.x); Ya[lr][lc + 1] = bf2f(va.y);
    Ya[lr][lc + 2] = bf2f(va.z); Ya[lr][lc + 3] = bf2f(va.w);
    Yc[lr][lc + 0] = bf2f(vc.x); Yc[lr][lc + 1] = bf2f(vc.y);
    Yc[lr][lc + 2] = bf2f(vc.z); Yc[lr][lc + 3] = bf2f(vc.w);
    __syncthreads();
    #pragma unroll
    for (int ii = 0; ii < 64; ++ii) acc += Ya[ii][tj] * Yc[ii][tk];
    __syncthreads();
  }
  atomicAdd(&Q[(bj + tj) * QS + bk + tk], acc);
  if (bj != bk) atomicAdd(&Q[(bk + tk) * QS + bj + tj], acc);
}

// ---------------- final: blocked Cholesky + blocked solves + trace ----------------
__global__ __launch_bounds__(512) void k_final(const float* __restrict__ Mg,
                                               const float* __restrict__ Qg,
                                               const float* __restrict__ tvec,
                                               const float* __restrict__ mvec,
                                               const float* __restrict__ scalars,
                                               const int* __restrict__ fds,
                                               float* __restrict__ out) {
  __shared__ float A[NP][NP];            // M (identity-padded) -> L (lower)
  __shared__ float Wm[NP][NP];           // S -> M^-1 S
  __shared__ float invd[NP];
  __shared__ float tl[NP], ml[NP];
  __shared__ float redA[8], redB[8];
  int tid = threadIdx.x;

  if (tid < NP) {
    tl[tid] = (tid < KP) ? tvec[tid] : 0.0f;
    ml[tid] = (tid < KP) ? mvec[tid] : 0.0f;
  }
  for (int idx = tid; idx < NP * NP; idx += 512) {
    int r = idx / NP, c = idx - r * NP;
    A[r][c] = (r < KP && c < KP) ? Mg[r * MS + c] : (r == c ? 1.0f : 0.0f);
  }
  __syncthreads();
  for (int idx = tid; idx < NP * NP; idx += 512) {
    int r = idx / NP, c = idx - r * NP;
    float s = 0.0f;
    if (r < KP && c < KP)
      s = Qg[r * QS + c] - tl[r] * ml[c] - ml[r] * tl[c] + (float)NROWS * ml[r] * ml[c];
    Wm[r][c] = s;
  }
  float logsum = 0.0f;
  __syncthreads();

  // ======== blocked Cholesky ========
  for (int p = 0; p < NP / NB; ++p) {
    int j0 = p * NB, j1 = j0 + NB;
    if (tid < 64) {
      int r = tid;
      int rr = (r < NB) ? r : 0;
      const float* arow = &A[j0 + rr][j0];
      float4 q0 = *reinterpret_cast<const float4*>(arow);
      float4 q1 = *reinterpret_cast<const float4*>(arow + 4);
      float4 q2 = *reinterpret_cast<const float4*>(arow + 8);
      float row[NB] = {q0.x, q0.y, q0.z, q0.w, q1.x, q1.y, q1.z, q1.w,
                       q2.x, q2.y, q2.z, q2.w};
      float mydiag = 1.0f;
      #pragma unroll
      for (int jj = 0; jj < NB; ++jj) {
        float s = sqrtf(__shfl(row[jj], jj));
        if (r == jj) { logsum += 2.0f * logf(s); mydiag = s; row[jj] = s; }
        else if (r > jj) row[jj] /= s;
        #pragma unroll
        for (int cc = jj + 1; cc < NB; ++cc) {
          float lc = __shfl(row[jj], cc);
          if (r > jj) row[cc] -= row[jj] * lc;
        }
      }
      if (r < NB) {
        float* wrow = &A[j0 + r][j0];
        #pragma unroll
        for (int k = 0; k < NB; ++k) if (k <= r) wrow[k] = row[k];
        invd[j0 + r] = 1.0f / mydiag;
      }
    }
    __syncthreads();
    int nbrows = NP - j1;
    if (tid < nbrows) {
      int r = j1 + tid;
      float* arow = &A[r][j0];
      float4 q0 = *reinterpret_cast<const float4*>(arow);
      float4 q1 = *reinterpret_cast<const float4*>(arow + 4);
      float4 q2 = *reinterpret_cast<const float4*>(arow + 8);
      float row[NB] = {q0.x, q0.y, q0.z, q0.w, q1.x, q1.y, q1.z, q1.w,
                       q2.x, q2.y, q2.z, q2.w};
      #pragma unroll
      for (int cc = 0; cc < NB; ++cc) {
        float a2 = row[cc];
        #pragma unroll
        for (int k = 0; k < NB; ++k) if (k < cc) a2 -= row[k] * A[j0 + cc][j0 + k];
        row[cc] = a2 * invd[j0 + cc];
      }
      float4 w0 = {row[0], row[1], row[2], row[3]};
      float4 w1 = {row[4], row[5], row[6], row[7]};
      float4 w2 = {row[8], row[9], row[10], row[11]};
      *reinterpret_cast<float4*>(arow) = w0;
      *reinterpret_cast<float4*>(arow + 4) = w1;
      *reinterpret_cast<float4*>(arow + 8) = w2;
    }
    __syncthreads();
    int nt4 = nbrows / 4;
    for (int t = tid; t < nt4 * nt4; t += 512) {
      int r4 = t / nt4, c4 = t - r4 * nt4;
      if (c4 > r4) continue;
      int r = j1 + r4 * 4, c = j1 + c4 * 4;
      float4 a0 = *reinterpret_cast<float4*>(&A[r + 0][c]);
      float4 a1 = *reinterpret_cast<float4*>(&A[r + 1][c]);
      float4 a2 = *reinterpret_cast<float4*>(&A[r + 2][c]);
      float4 a3 = *reinterpret_cast<float4*>(&A[r + 3][c]);
      #pragma unroll
      for (int k = 0; k < NB; ++k) {
        float pc0 = A[c + 0][j0 + k], pc1 = A[c + 1][j0 + k];
        float pc2 = A[c + 2][j0 + k], pc3 = A[c + 3][j0 + k];
        float pr0 = A[r + 0][j0 + k], pr1 = A[r + 1][j0 + k];
        float pr2 = A[r + 2][j0 + k], pr3 = A[r + 3][j0 + k];
        a0.x -= pr0 * pc0; a0.y -= pr0 * pc1; a0.z -= pr0 * pc2; a0.w -= pr0 * pc3;
        a1.x -= pr1 * pc0; a1.y -= pr1 * pc1; a1.z -= pr1 * pc2; a1.w -= pr1 * pc3;
        a2.x -= pr2 * pc0; a2.y -= pr2 * pc1; a2.z -= pr2 * pc2; a2.w -= pr2 * pc3;
        a3.x -= pr3 * pc0; a3.y -= pr3 * pc1; a3.z -= pr3 * pc2; a3.w -= pr3 * pc3;
      }
      *reinterpret_cast<float4*>(&A[r + 0][c]) = a0;
      *reinterpret_cast<float4*>(&A[r + 1][c]) = a1;
      *reinterpret_cast<float4*>(&A[r + 2][c]) = a2;
      *reinterpret_cast<float4*>(&A[r + 3][c]) = a3;
    }
    __syncthreads();
  }

  // ======== forward solve: L W = S ========
  for (int p = 0; p < NP / NB; ++p) {
    int j0 = p * NB, j1 = j0 + NB;
    if (tid < NP) {
      int c = tid;
      float w[NB];
      #pragma unroll
      for (int k = 0; k < NB; ++k) w[k] = Wm[j0 + k][c];
      #pragma unroll
      for (int kk = 0; kk < NB; ++kk) {
        float a2 = w[kk];
        #pragma unroll
        for (int k = 0; k < NB; ++k) if (k < kk) a2 -= A[j0 + kk][j0 + k] * w[k];
        w[kk] = a2 * invd[j0 + kk];
      }
      #pragma unroll
      for (int k = 0; k < NB; ++k) Wm[j0 + k][c] = w[k];
    }
    __syncthreads();
    int nbrows = NP - j1;
    int nr4 = nbrows / 4, nc4 = NP / 4;
    for (int t = tid; t < nr4 * nc4; t += 512) {
      int r4 = t / nc4, c4 = t - r4 * nc4;
      int r = j1 + r4 * 4, c = c4 * 4;
      float4 a0 = *reinterpret_cast<float4*>(&Wm[r + 0][c]);
      float4 a1 = *reinterpret_cast<float4*>(&Wm[r + 1][c]);
      float4 a2 = *reinterpret_cast<float4*>(&Wm[r + 2][c]);
      float4 a3 = *reinterpret_cast<float4*>(&Wm[r + 3][c]);
      #pragma unroll
      for (int k = 0; k < NB; ++k) {
        float l0 = A[r + 0][j0 + k], l1 = A[r + 1][j0 + k];
        float l2 = A[r + 2][j0 + k], l3 = A[r + 3][j0 + k];
        float4 wr = *reinterpret_cast<const float4*>(&Wm[j0 + k][c]);
        a0.x -= l0 * wr.x; a0.y -= l0 * wr.y; a0.z -= l0 * wr.z; a0.w -= l0 * wr.w;
        a1.x -= l1 * wr.x; a1.y -= l1 * wr.y; a1.z -= l1 * wr.z; a1.w -= l1 * wr.w;
        a2.x -= l2 * wr.x; a2.y -= l2 * wr.y; a2.z -= l2 * wr.z; a2.w -= l2 * wr.w;
        a3.x -= l3 * wr.x; a3.y -= l3 * wr.y; a3.z -= l3 * wr.z; a3.w -= l3 * wr.w;
      }
      *reinterpret_cast<float4*>(&Wm[r + 0][c]) = a0;
      *reinterpret_cast<float4*>(&Wm[r + 1][c]) = a1;
      *reinterpret_cast<float4*>(&Wm[r + 2][c]) = a2;
      *reinterpret_cast<float4*>(&Wm[r + 3][c]) = a3;
    }
    __syncthreads();
  }

  // ======== backward solve: L^T U = W ========
  for (int p = NP / NB - 1; p >= 0; --p) {
    int j0 = p * NB;
    if (tid < NP) {
      int c = tid;
      float w[NB];
      #pragma unroll
      for (int k = 0; k < NB; ++k) w[k] = Wm[j0 + k][c];
      #pragma unroll
      for (int kk = NB - 1; kk >= 0; --kk) {
        float a2 = w[kk];
        #pragma unroll
        for (int k = 0; k < NB; ++k) if (k > kk) a2 -= A[j0 + k][j0 + kk] * w[k];
        w[kk] = a2 * invd[j0 + kk];
      }
      #pragma unroll
      for (int k = 0; k < NB; ++k) Wm[j0 + k][c] = w[k];
    }
    __syncthreads();
    int nr4 = j0 / 4, nc4 = NP / 4;
    for (int t = tid; t < nr4 * nc4; t += 512) {
      int r4 = t / nc4, c4 = t - r4 * nc4;
      int r = r4 * 4, c = c4 * 4;
      float4 a0 = *reinterpret_cast<float4*>(&Wm[r + 0][c]);
      float4 a1 = *reinterpret_cast<float4*>(&Wm[r + 1][c]);
      float4 a2 = *reinterpret_cast<float4*>(&Wm[r + 2][c]);
      float4 a3 = *reinterpret_cast<float4*>(&Wm[r + 3][c]);
      #pragma unroll
      for (int k = 0; k < NB; ++k) {
        float l0 = A[j0 + k][r + 0], l1 = A[j0 + k][r + 1];
        float l2 = A[j0 + k][r + 2], l3 = A[j0 + k][r + 3];
        float4 wr = *reinterpret_cast<const float4*>(&Wm[j0 + k][c]);
        a0.x -= l0 * wr.x; a0.y -= l0 * wr.y; a0.z -= l0 * wr.z; a0.w -= l0 * wr.w;
        a1.x -= l1 * wr.x; a1.y -= l1 * wr.y; a1.z -= l1 * wr.z; a1.w -= l1 * wr.w;
        a2.x -= l2 * wr.x; a2.y -= l2 * wr.y; a2.z -= l2 * wr.z; a2.w -= l2 * wr.w;
        a3.x -= l3 * wr.x; a3.y -= l3 * wr.y; a3.z -= l3 * wr.z; a3.w -= l3 * wr.w;
      }
      *reinterpret_cast<float4*>(&Wm[r + 0][c]) = a0;
      *reinterpret_cast<float4*>(&Wm[r + 1][c]) = a1;
      *reinterpret_cast<float4*>(&Wm[r + 2][c]) = a2;
      *reinterpret_cast<float4*>(&Wm[r + 3][c]) = a3;
    }
    __syncthreads();
  }

  // ======== trace + logdet + combine ========
  float dv = (tid < KP) ? Wm[tid][tid] : 0.0f;
  float v1 = dv, v2 = logsum;
  #pragma unroll
  for (int off = 32; off > 0; off >>= 1) {
    v1 += __shfl_down(v1, off, 64);
    v2 += __shfl_down(v2, off, 64);
  }
  if ((tid & 63) == 0) { redA[tid >> 6] = v1; redB[tid >> 6] = v2; }
  __syncthreads();
  if (tid == 0) {
    float tr = 0.0f, logdetM = 0.0f;
    #pragma unroll
    for (int i = 0; i < 8; ++i) { tr += redA[i]; logdetM += redB[i]; }
    double sumlog = (double)scalars[0];
    double term1  = (double)scalars[1];
    double total = (double)NROWS * (double)D * LOG2PI
                 + (double)NROWS * (sumlog + (double)logdetM)
                 + term1 - (double)tr;
    double scale = (double)fds[0] / (double)NROWS;
    out[0] = (float)(scale * (-0.5) * total);
  }
}

// ---------------- launch ----------------
extern "C" void kernel_launch(void* const* d_in, const int* in_sizes, int n_in,
                              void* d_out, int out_size, void* d_ws, size_t ws_size,
                              hipStream_t stream) {
  const float* x     = (const float*)d_in[0];
  const float* theta = (const float*)d_in[1];
  const int*   fds   = (const int*)d_in[2];
  float* out = (float*)d_out;
  char* ws = (char*)d_ws;

  unsigned short* Yb  = (unsigned short*)ws;                       // 8192*144*2 = 2359296
  unsigned short* VbT = (unsigned short*)(ws + 2359296);           // 144*4096*2 = 1179648
  float* Q        = (float*)(ws + 2359296 + 1179648);              // QS*QS*4 = 82944
  float* colsum   = (float*)(ws + 2359296 + 1179648 + 82944);      // D*4
  float* colsumsq = colsum + D;                                    // D*4
  float* M        = colsumsq + D;                                  // KP*MS*4
  float* tvec     = M + KP * MS;
  float* mvec     = tvec + MS;
  float* scalars  = mvec + MS;

  // zero atomic accumulators: Q + colsum + colsumsq (contiguous)
  hipMemsetAsync(Q, 0, (size_t)(QS * QS + 2 * D) * sizeof(float), stream);

  k_prep     <<<dim3(NC), 256, 0, stream>>>(theta, VbT);
  k_colstats <<<dim3(D / 4 / 256, 64), 256, 0, stream>>>(x, colsum, colsumsq);
  k_gemm     <<<dim3(NROWS / GBM), 512, 0, stream>>>(x, VbT, Yb);
  k_M        <<<dim3(KP, KP), 256, 0, stream>>>(theta, VbT, M);
  k_scalars  <<<dim3(1), 256, 0, stream>>>(theta, colsum, colsumsq, scalars);
  k_smallvecs<<<dim3(KP, 2), 256, 0, stream>>>(theta, VbT, colsum, tvec, mvec);
  k_syrk     <<<dim3(QS / 16, QS / 16, SYRK_ZSPLIT), 256, 0, stream>>>(Yb, Q);
  k_final    <<<dim3(1), 512, 0, stream>>>(M, Q, tvec, mvec, scalars, fds, out);
}